// Round 6
// baseline (144.369 us; speedup 1.0000x reference)
//
#include <hip/hip_runtime.h>

typedef __bf16 bf16x4 __attribute__((ext_vector_type(4)));
typedef __bf16 bf16x8 __attribute__((ext_vector_type(8)));
typedef float floatx4 __attribute__((ext_vector_type(4)));

constexpr int Bc = 4, Hc = 8, Nc = 2048, Dc = 64;
constexpr int BQ = 128;      // q-rows per block
constexpr int TK = 64;       // keys per tile
constexpr int NT = Nc / TK;  // 32 tiles
constexpr int SPS = 40;      // sP row stride (bf16): 80 B rows, 16B-aligned
constexpr float LOG2E = 1.44269504088896340736f;

// ws layout (~17.04 MB):
//   Ksw: [bh][jt] 8 KiB image, chunk g = key*8 + (kc ^ (key&7)) = K[key][kc*8..+7] bf16
//   Vsw: [bh][jt] 8 KiB image, chunk g = d*8   + (kc ^ (d&7))   = V^T[d][kc*8..+7] bf16
//   kkn: [bh][key] fp32 = -(sum K^2)*0.125*log2e
constexpr size_t KSW_OFF = 0;
constexpr size_t VSW_OFF = (size_t)32 * NT * 8192;   // 8 MiB
constexpr size_t KKN_OFF = VSW_OFF * 2;              // 16 MiB

typedef __attribute__((address_space(1))) const unsigned int gu32;
typedef __attribute__((address_space(3))) unsigned int lu32;
__device__ __forceinline__ void dma16(const void* g, void* l) {
    __builtin_amdgcn_global_load_lds((gu32*)g, (lu32*)l, 16, 0, 0);
}
__device__ __forceinline__ void dma4(const void* g, void* l) {
    __builtin_amdgcn_global_load_lds((gu32*)g, (lu32*)l, 4, 0, 0);
}

// ---------------- prep v2 (verified round 5): fully-coalesced image builder ----------------
__global__ __launch_bounds__(256) void prep_kernel(
    const float* __restrict__ Kg, const float* __restrict__ Vg, char* __restrict__ ws)
{
    __shared__ float sT[64 * 68];   // V tile [key][d], stride 68
    const int tid = threadIdx.x;
    const int jt = blockIdx.x, bh = blockIdx.y;

    __bf16* Ksw = (__bf16*)(ws + KSW_OFF) + ((size_t)bh * NT + jt) * 4096;
    __bf16* Vsw = (__bf16*)(ws + VSW_OFF) + ((size_t)bh * NT + jt) * 4096;
    float*  kkn = (float*)(ws + KKN_OFF) + (size_t)bh * Nc + jt * 64;
    const size_t tb = ((size_t)bh * Nc + jt * 64) * Dc;

#pragma unroll
    for (int cc = 0; cc < 2; ++cc) {
        const int g   = tid + cc * 256;
        const int key = g >> 3, kcx = g & 7;
        const int kc  = kcx ^ (key & 7);
        const float* src = Kg + tb + key * 64 + kc * 8;
        float4 a = *(const float4*)src;
        float4 b = *(const float4*)(src + 4);
        float ss = a.x*a.x + a.y*a.y + a.z*a.z + a.w*a.w
                 + b.x*b.x + b.y*b.y + b.z*b.z + b.w*b.w;
        ss += __shfl_xor(ss, 1);
        ss += __shfl_xor(ss, 2);
        ss += __shfl_xor(ss, 4);
        if (kcx == 0) kkn[key] = -(ss * 0.125f * LOG2E);
        bf16x8 c8;
        c8[0]=(__bf16)a.x; c8[1]=(__bf16)a.y; c8[2]=(__bf16)a.z; c8[3]=(__bf16)a.w;
        c8[4]=(__bf16)b.x; c8[5]=(__bf16)b.y; c8[6]=(__bf16)b.z; c8[7]=(__bf16)b.w;
        *(bf16x8*)(Ksw + g * 8) = c8;
    }
    {
        const int js = tid >> 2, dc = (tid & 3) * 16;
        const float* vr = Vg + tb + js * 64 + dc;
        float* dst = &sT[js * 68 + dc];
        *(float4*)dst       = *(const float4*)vr;
        *(float4*)(dst + 4) = *(const float4*)(vr + 4);
        *(float4*)(dst + 8) = *(const float4*)(vr + 8);
        *(float4*)(dst + 12)= *(const float4*)(vr + 12);
    }
    __syncthreads();
#pragma unroll
    for (int cc = 0; cc < 2; ++cc) {
        const int g = tid + cc * 256;
        const int d = g >> 3, kcx = g & 7;
        const int kc = kcx ^ (d & 7);
        bf16x8 c8;
#pragma unroll
        for (int e = 0; e < 8; ++e) {
            const int ee = (e + kcx) & 7;
            c8[ee] = (__bf16)sT[(kc * 8 + ee) * 68 + d];
        }
        *(bf16x8*)(Vsw + g * 8) = c8;
    }
}

// ---------------- main fused attention: split-K across waves ----------------
// Wave (kh=w>>1, qh=w&1): keys kh*32..+31 of each tile, queries qh*64..+63.
// l and O are pure sums (exp2 args bounded, no online max) -> partials combine
// in a 2-phase barrier-separated epilogue through dedicated sO/sl arrays.
__global__ __launch_bounds__(256, 2) void attn_kernel(
    const float* __restrict__ Qg, const char* __restrict__ ws, float* __restrict__ Og)
{
    __shared__ __align__(16) __bf16 sK[2][4096];
    __shared__ __align__(16) __bf16 sV[2][4096];
    __shared__ __align__(16) float  skk[2][64];
    __shared__ __align__(16) __bf16 sP[4][64 * SPS];  // per-wave [q64][key32]
    __shared__ __align__(16) float  sl[256];          // [kh][qh*64+q']
    __shared__ __align__(16) float  sO[64 * 68];      // one qh-half exchange

    const int tid  = threadIdx.x;
    const int wave = tid >> 6;
    const int lane = tid & 63;
    const int qd   = lane >> 4;
    const int c    = lane & 15;
    const int kh   = wave >> 1;   // key half
    const int qh   = wave & 1;    // query half

    const int qt = blockIdx.x;    // 0..15
    const int bh = blockIdx.y;    // 0..31

    const char* Kimg = ws + KSW_OFF + (size_t)bh * NT * 8192;
    const char* Vimg = ws + VSW_OFF + (size_t)bh * NT * 8192;
    const float* kkp = (const float*)(ws + KKN_OFF) + (size_t)bh * Nc;

    const float qscale = 0.25f * LOG2E;
    const int i0 = qt * BQ + qh * 64;

    // Q fragments (B-operand): qf[h4][ks] = Q[i0+h4*16+c][ks*32+qd*8+j]*qscale
    bf16x8 qf[4][2];
#pragma unroll
    for (int h4 = 0; h4 < 4; ++h4) {
        const float* qrow = Qg + ((size_t)bh * Nc + i0 + h4 * 16 + c) * Dc + qd * 8;
#pragma unroll
        for (int ks = 0; ks < 2; ++ks) {
            float4 a = *(const float4*)(qrow + ks * 32);
            float4 b = *(const float4*)(qrow + ks * 32 + 4);
            bf16x8 f;
            f[0] = (__bf16)(a.x * qscale); f[1] = (__bf16)(a.y * qscale);
            f[2] = (__bf16)(a.z * qscale); f[3] = (__bf16)(a.w * qscale);
            f[4] = (__bf16)(b.x * qscale); f[5] = (__bf16)(b.y * qscale);
            f[6] = (__bf16)(b.z * qscale); f[7] = (__bf16)(b.w * qscale);
            qf[h4][ks] = f;
        }
    }

    // fragment elem-offsets into the 8KiB images
    int koffK[2][2], voff[4];
#pragma unroll
    for (int kt = 0; kt < 2; ++kt)
#pragma unroll
        for (int ks = 0; ks < 2; ++ks) {
            const int key = kh * 32 + kt * 16 + c;
            koffK[kt][ks] = key * 64 + (((ks * 4 + qd) ^ (key & 7)) << 3);
        }
#pragma unroll
    for (int dt = 0; dt < 4; ++dt) {
        const int d = dt * 16 + c;
        voff[dt] = d * 64 + (((kh * 4 + qd) ^ (d & 7)) << 3);
    }

    floatx4 oacc[4][4];
#pragma unroll
    for (int h4 = 0; h4 < 4; ++h4)
#pragma unroll
        for (int dt = 0; dt < 4; ++dt)
#pragma unroll
            for (int e = 0; e < 4; ++e) oacc[h4][dt][e] = 0.f;
    float lp[4] = {0.f, 0.f, 0.f, 0.f};

    auto stage = [&](int jt2, int b) {
        const char* ki = Kimg + (size_t)jt2 * 8192;
        const char* vi = Vimg + (size_t)jt2 * 8192;
#pragma unroll
        for (int i = 0; i < 2; ++i) {
            const int off = wave * 2048 + i * 1024;
            dma16(ki + off + lane * 16, (char*)&sK[b][0] + off);
            dma16(vi + off + lane * 16, (char*)&sV[b][0] + off);
        }
        if (wave == 3) dma4(kkp + jt2 * 64 + lane, &skk[b][0]);
    };

    stage(0, 0);

    __bf16* sPw = &sP[wave][0];

    for (int jt = 0; jt < NT; ++jt) {
        const int b = jt & 1;
        __syncthreads();                        // buf b staged; buf b^1 free
        if (jt + 1 < NT) stage(jt + 1, b ^ 1);  // drains at next barrier

        // S^T = K.Q^T per 16-key subtile; acc init = -kk*scale (bias folded)
#pragma unroll
        for (int kt = 0; kt < 2; ++kt) {
            floatx4 kkf = *(const floatx4*)&skk[b][kh * 32 + kt * 16 + qd * 4];
            floatx4 st[4];
#pragma unroll
            for (int h4 = 0; h4 < 4; ++h4) st[h4] = kkf;
#pragma unroll
            for (int ks = 0; ks < 2; ++ks) {
                bf16x8 kf = *(const bf16x8*)(&sK[b][0] + koffK[kt][ks]);
                st[0] = __builtin_amdgcn_mfma_f32_16x16x32_bf16(kf, qf[0][ks], st[0], 0, 0, 0);
                st[1] = __builtin_amdgcn_mfma_f32_16x16x32_bf16(kf, qf[1][ks], st[1], 0, 0, 0);
                st[2] = __builtin_amdgcn_mfma_f32_16x16x32_bf16(kf, qf[2][ks], st[2], 0, 0, 0);
                st[3] = __builtin_amdgcn_mfma_f32_16x16x32_bf16(kf, qf[3][ks], st[3], 0, 0, 0);
            }
            // p = exp2; accumulate l; pack bf16 into sP[wave][query][key32]
#pragma unroll
            for (int h4 = 0; h4 < 4; ++h4) {
                float p0 = __builtin_amdgcn_exp2f(st[h4][0]);
                float p1 = __builtin_amdgcn_exp2f(st[h4][1]);
                float p2 = __builtin_amdgcn_exp2f(st[h4][2]);
                float p3 = __builtin_amdgcn_exp2f(st[h4][3]);
                lp[h4] += (p0 + p1) + (p2 + p3);
                bf16x4 pk;
                pk[0] = (__bf16)p0; pk[1] = (__bf16)p1;
                pk[2] = (__bf16)p2; pk[3] = (__bf16)p3;
                *(bf16x4*)&sPw[(h4 * 16 + c) * SPS + kt * 16 + qd * 4] = pk;
            }
        }

        // P back in A-layout (same-wave region; lgkmcnt-ordered, no barrier)
        bf16x8 pf[4];
#pragma unroll
        for (int h4 = 0; h4 < 4; ++h4)
            pf[h4] = *(const bf16x8*)&sPw[(h4 * 16 + c) * SPS + qd * 8];

        // O += P.V over this wave's 32 keys (single K=32 MFMA per (h4,dt))
#pragma unroll
        for (int dt = 0; dt < 4; ++dt) {
            bf16x8 vf = *(const bf16x8*)(&sV[b][0] + voff[dt]);
            oacc[0][dt] = __builtin_amdgcn_mfma_f32_16x16x32_bf16(pf[0], vf, oacc[0][dt], 0, 0, 0);
            oacc[1][dt] = __builtin_amdgcn_mfma_f32_16x16x32_bf16(pf[1], vf, oacc[1][dt], 0, 0, 0);
            oacc[2][dt] = __builtin_amdgcn_mfma_f32_16x16x32_bf16(pf[2], vf, oacc[2][dt], 0, 0, 0);
            oacc[3][dt] = __builtin_amdgcn_mfma_f32_16x16x32_bf16(pf[3], vf, oacc[3][dt], 0, 0, 0);
        }
    }

    // ---- epilogue ----
    // partial l per query (reduce over qd within wave)
#pragma unroll
    for (int h4 = 0; h4 < 4; ++h4) {
        float l = lp[h4];
        l += __shfl_xor(l, 16);
        l += __shfl_xor(l, 32);
        if (qd == 0) sl[kh * 128 + qh * 64 + h4 * 16 + c] = l;
    }
    __syncthreads();   // all loop LDS traffic + sl writes complete

    const int b_ = bh >> 3, hh = bh & 7;
#pragma unroll
    for (int ph = 0; ph < 2; ++ph) {
        if (kh == 0 && qh == ph) {   // park kh=0 partial for this query half
#pragma unroll
            for (int h4 = 0; h4 < 4; ++h4)
#pragma unroll
                for (int dt = 0; dt < 4; ++dt)
#pragma unroll
                    for (int r = 0; r < 4; ++r)
                        sO[(h4 * 16 + qd * 4 + r) * 68 + dt * 16 + c] = oacc[h4][dt][r];
        }
        __syncthreads();
        if (kh == 1 && qh == ph) {   // combine, normalize, store [B,N,H,D]
#pragma unroll
            for (int h4 = 0; h4 < 4; ++h4) {
                floatx4 l0 = *(const floatx4*)&sl[qh * 64 + h4 * 16 + qd * 4];
                floatx4 l1 = *(const floatx4*)&sl[128 + qh * 64 + h4 * 16 + qd * 4];
#pragma unroll
                for (int r = 0; r < 4; ++r) {
                    const float inv = 1.f / (l0[r] + l1[r]);
                    const int i = i0 + h4 * 16 + qd * 4 + r;
                    float* orow = Og + (((size_t)b_ * Nc + i) * Hc + hh) * Dc + c;
#pragma unroll
                    for (int dt = 0; dt < 4; ++dt) {
                        const float part = sO[(h4 * 16 + qd * 4 + r) * 68 + dt * 16 + c];
                        orow[dt * 16] = (oacc[h4][dt][r] + part) * inv;
                    }
                }
            }
        }
        __syncthreads();
    }
}

extern "C" void kernel_launch(void* const* d_in, const int* in_sizes, int n_in,
                              void* d_out, int out_size, void* d_ws, size_t ws_size,
                              hipStream_t stream) {
    const float* q = (const float*)d_in[0];
    const float* k = (const float*)d_in[1];
    const float* v = (const float*)d_in[2];
    float* out = (float*)d_out;
    char* ws = (char*)d_ws;   // ~17.04 MB
    prep_kernel<<<dim3(NT, Bc * Hc), 256, 0, stream>>>(k, v, ws);
    attn_kernel<<<dim3(Nc / BQ, Bc * Hc), 256, 0, stream>>>(q, ws, out);
}